// Round 12
// baseline (385.369 us; speedup 1.0000x reference)
//
#include <hip/hip_runtime.h>
#include <hip/hip_fp16.h>
#include <stdint.h>

#define N_NODES 100000
#define N_EDGES 640000
#define R_REL   64
#define D_DIM   128
#define L_LAYERS 2

#define CAP 32            // bucket capacity per node (P(deg>=32)~4e-13; verified no drops R8-R11)

#define LDA 136   // bf16 tile stride (128 + 8 pad)
#define LDT 264   // bf16 t-tile stride (256 + 8 pad)
#define LDFY 132  // f32 y-tile stride (128 + 4 pad)
#define LDP 264   // f16 prep activation stride (256 + 8 pad)
#define MROWS 128 // mlp/xw tile rows
#define GMLP ((N_NODES + MROWS - 1) / MROWS)   // 782

#define SCAT_BLKS  (N_EDGES / 512)   // 1250 (512 thr/block)
#define PREP_BLKS  2                 // prep role (one per layer l)
#define CONV_BLKS  128               // weight convert role (512 thr each)
#define SPC_BLKS   (SCAT_BLKS + PREP_BLKS + CONV_BLKS)   // 1380

typedef __attribute__((ext_vector_type(8))) short    short8;   // 8 bf16 MFMA frag
typedef __attribute__((ext_vector_type(8))) _Float16 half8;    // 8 f16 MFMA frag
typedef __attribute__((ext_vector_type(4))) unsigned short ushort4v;
typedef __attribute__((ext_vector_type(4))) float    f32x4;

__device__ __forceinline__ unsigned short f32_to_bf16(float f) {
  union { float f; uint32_t u; } v; v.f = f;
  uint32_t u = v.u;
  u += 0x7fffu + ((u >> 16) & 1u);   // RNE (finite inputs only)
  return (unsigned short)(u >> 16);
}
__device__ __forceinline__ unsigned short f2h(float f) {
  __half h = __float2half(f);
  return __half_as_ushort(h);
}
__device__ __forceinline__ __half2 u2h(unsigned int u) {
  union { unsigned int u; __half2 h; } v; v.u = u; return v.h;
}
__device__ __forceinline__ short8 frag_from_f32(const float* p) {
  float4 a = *(const float4*)p;
  float4 b = *(const float4*)(p + 4);
  short8 r;
  r[0] = (short)f32_to_bf16(a.x); r[1] = (short)f32_to_bf16(a.y);
  r[2] = (short)f32_to_bf16(a.z); r[3] = (short)f32_to_bf16(a.w);
  r[4] = (short)f32_to_bf16(b.x); r[5] = (short)f32_to_bf16(b.y);
  r[6] = (short)f32_to_bf16(b.z); r[7] = (short)f32_to_bf16(b.w);
  return r;
}
__device__ __forceinline__ half8 hfrag_from_f32(const float* p) {
  float4 a = *(const float4*)p;
  float4 b = *(const float4*)(p + 4);
  half8 r;
  r[0] = (_Float16)a.x; r[1] = (_Float16)a.y;
  r[2] = (_Float16)a.z; r[3] = (_Float16)a.w;
  r[4] = (_Float16)b.x; r[5] = (_Float16)b.y;
  r[6] = (_Float16)b.z; r[7] = (_Float16)b.w;
  return r;
}

// ---------------------------------------------------------------------------
// prep GEMM phase (8 waves x 32 cols). f16 MFMA, f32 acc; final phase writes
// packed gbb: lane layout {g2l,g2l+1,b2l,b2l+1} at t*256+l*4.
// ---------------------------------------------------------------------------
template<int K, bool RELU, bool FINAL>
__device__ __forceinline__ void prep_gemm(const unsigned short* __restrict__ inb,
                                          const float* __restrict__ W,
                                          const float* __restrict__ bias,
                                          unsigned short* __restrict__ outb,
                                          unsigned short* __restrict__ gbb_l,
                                          int wave, int lrow, int quad) {
  const int n0 = wave * 32;
  f32x4 acc[4][2] = {};
  for (int ks = 0; ks < K; ks += 32) {
    half8 bf[2];
    #pragma unroll
    for (int nt = 0; nt < 2; ++nt)
      bf[nt] = hfrag_from_f32(&W[(size_t)(n0 + nt * 16 + lrow) * K + ks + quad * 8]);
    #pragma unroll
    for (int mt = 0; mt < 4; ++mt) {
      half8 a = *(const half8*)&inb[(mt * 16 + lrow) * LDP + ks + quad * 8];
      #pragma unroll
      for (int nt = 0; nt < 2; ++nt)
        acc[mt][nt] = __builtin_amdgcn_mfma_f32_16x16x32_f16(a, bf[nt], acc[mt][nt], 0, 0, 0);
    }
  }
  #pragma unroll
  for (int mt = 0; mt < 4; ++mt)
    #pragma unroll
    for (int nt = 0; nt < 2; ++nt) {
      int col = n0 + nt * 16 + lrow;
      float bb = bias[col];
      #pragma unroll
      for (int rr = 0; rr < 4; ++rr) {
        int row = mt * 16 + quad * 4 + rr;
        float v = acc[mt][nt][rr] + bb;
        if (RELU) v = fmaxf(v, 0.f);
        if (!FINAL) {
          outb[row * LDP + col] = f2h(v);
        } else {
          int slot = (col < D_DIM) ? ((col >> 1) * 4 + (col & 1))
                                   : (((col - D_DIM) >> 1) * 4 + 2 + ((col - D_DIM) & 1));
          gbb_l[row * 256 + slot] = f2h(v);
        }
      }
    }
}

// ---------------------------------------------------------------------------
// scatter ∪ prep ∪ conv: the atomic pass overlapped with the two tiny
// streaming roles (~3MB total — NOT R8's 51MB xw stream, which is what
// collapsed the mega-kernel; commit: if this >120us, de-fuse permanently).
//  [0, 1250)      bucket scatter (512 thr): slot=atomicAdd(cnt[dst]);
//                 bucket[dst*32+slot] = src | (type<<17)
//  [1250, 1252)   prep: 4-layer GEMM chain -> packed gbb (8 waves, MFMA)
//  [1252, 1380)   weight f32->bf16 conversion
// ---------------------------------------------------------------------------
__global__ __launch_bounds__(512)
void scatter_prep_conv_kernel(const int* __restrict__ ei, const int* __restrict__ et,
                              int* __restrict__ cnt, unsigned int* __restrict__ bucket,
                              const float* __restrict__ rel_emb,
                              const float* __restrict__ rmw0, const float* __restrict__ rmb0,
                              const float* __restrict__ rmw1, const float* __restrict__ rmb1,
                              const float* __restrict__ rmw2, const float* __restrict__ rmb2,
                              const float* __restrict__ rmw3, const float* __restrict__ rmb3,
                              unsigned short* __restrict__ gbb,
                              const float* __restrict__ Ww, const float* __restrict__ mw0,
                              const float* __restrict__ mw1,
                              unsigned short* __restrict__ Wwb, unsigned short* __restrict__ mw0b,
                              unsigned short* __restrict__ mw1b) {
  __shared__ unsigned short u_lds[2 * 64 * LDP];   // 67584 B (prep role only)
  const int b = blockIdx.x;
  const int tid = threadIdx.x;     // 0..511

  if (b < SCAT_BLKS) {                         // ---- scatter role
    int idx = b * 512 + tid;
    int dst = ei[N_EDGES + idx];
    int slot = atomicAdd(&cnt[dst], 1);
    if (slot < CAP)
      bucket[(size_t)dst * CAP + slot] =
          (unsigned int)ei[idx] | ((unsigned int)et[idx] << 17);
    return;
  }

  const int wave = tid >> 6, lane = tid & 63;
  const int lrow = lane & 15, quad = lane >> 4;

  if (b < SCAT_BLKS + PREP_BLKS) {             // ---- prep role (l = b - SCAT_BLKS)
    unsigned short* bufX = u_lds;              // [64][LDP]
    unsigned short* bufY = u_lds + 64 * LDP;
    const int l = b - SCAT_BLKS;
    for (int i = tid; i < 64 * 32; i += 512) {
      int row = i >> 5, c4 = i & 31;
      float4 v = *(const float4*)&rel_emb[(size_t)(l * R_REL + row) * D_DIM + c4 * 4];
      ushort4v s;
      s[0] = f2h(v.x); s[1] = f2h(v.y); s[2] = f2h(v.z); s[3] = f2h(v.w);
      *(ushort4v*)&bufX[row * LDP + c4 * 4] = s;
    }
    __syncthreads();
    prep_gemm<128, true, false>(bufX, rmw0 + (size_t)l * 256 * 128, rmb0 + l * 256,
                                bufY, nullptr, wave, lrow, quad);
    __syncthreads();
    prep_gemm<256, true, false>(bufY, rmw1 + (size_t)l * 256 * 256, rmb1 + l * 256,
                                bufX, nullptr, wave, lrow, quad);
    __syncthreads();
    prep_gemm<256, true, false>(bufX, rmw2 + (size_t)l * 256 * 256, rmb2 + l * 256,
                                bufY, nullptr, wave, lrow, quad);
    __syncthreads();
    prep_gemm<256, false, true>(bufY, rmw3 + (size_t)l * 256 * 256, rmb3 + l * 256,
                                nullptr, gbb + (size_t)l * R_REL * 256, wave, lrow, quad);
    return;
  }

  // ---- weight convert role
  {
    int i = (b - SCAT_BLKS - PREP_BLKS) * 512 + tid;   // 0..65535
    if (i < L_LAYERS * D_DIM * D_DIM)     Wwb[i]  = f32_to_bf16(Ww[i]);
    if (i < L_LAYERS * 2 * D_DIM * D_DIM) mw0b[i] = f32_to_bf16(mw0[i]);
    if (i < L_LAYERS * 2 * D_DIM * D_DIM) mw1b[i] = f32_to_bf16(mw1[i]);
  }
}

// ---------------------------------------------------------------------------
// xw(L0): slim standalone kernel (R11 fix: was paying prep's 67.6KB LDS ->
// 2 blocks/CU and a 1.53-round tail; at 34.8KB -> 4 blocks/CU, 782 blocks
// fit in ONE occupancy round). 128-row tiles, 8 MFMA per weight load,
// LDS-staged full-row output writes.
// ---------------------------------------------------------------------------
__global__ __launch_bounds__(512, 8)
void xw_kernel(const float* __restrict__ x, const float* __restrict__ Ww,
               const float* __restrict__ Wb, unsigned short* __restrict__ xwb) {
  __shared__ unsigned short a_lds[MROWS * LDA];   // 34816 B
  const int tid = threadIdx.x;     // 0..511
  const int m0 = blockIdx.x * MROWS;
  const int wave = tid >> 6, lane = tid & 63;
  const int lrow = lane & 15, quad = lane >> 4;

  for (int i = tid; i < MROWS * 32; i += 512) {
    int row = i >> 5, c4 = i & 31;
    int rg = m0 + row; if (rg >= N_NODES) rg = N_NODES - 1;
    float4 v = *(const float4*)&x[(size_t)rg * D_DIM + c4 * 4];
    ushort4v s;
    s[0] = f32_to_bf16(v.x); s[1] = f32_to_bf16(v.y);
    s[2] = f32_to_bf16(v.z); s[3] = f32_to_bf16(v.w);
    *(ushort4v*)&a_lds[row * LDA + c4 * 4] = s;
  }
  __syncthreads();

  const int n0 = wave * 16;
  f32x4 acc[8] = {};
  #pragma unroll
  for (int ks = 0; ks < 128; ks += 32) {
    short8 bf = frag_from_f32(&Ww[(size_t)(n0 + lrow) * D_DIM + ks + quad * 8]);
    #pragma unroll
    for (int mt = 0; mt < 8; ++mt) {
      short8 a = *(const short8*)&a_lds[(mt * 16 + lrow) * LDA + ks + quad * 8];
      acc[mt] = __builtin_amdgcn_mfma_f32_16x16x32_bf16(a, bf, acc[mt], 0, 0, 0);
    }
  }
  __syncthreads();   // a tile dead -> overlay xw f16 tile
  float bb = Wb[n0 + lrow];
  #pragma unroll
  for (int mt = 0; mt < 8; ++mt)
    #pragma unroll
    for (int rr = 0; rr < 4; ++rr) {
      int row = mt * 16 + quad * 4 + rr;
      a_lds[row * LDA + n0 + lrow] = f2h(acc[mt][rr] + bb);
    }
  __syncthreads();
  // cooperative full-row writes (short8): no partial-line amplification
  for (int i = tid; i < MROWS * 16; i += 512) {
    int row = i >> 4, seg = i & 15;
    int rg = m0 + row;
    if (rg < N_NODES)
      *(short8*)&xwb[(size_t)rg * D_DIM + seg * 8] = *(const short8*)&a_lds[row * LDA + seg * 8];
  }
}

// ---------------------------------------------------------------------------
// agg: one WAVE per node. Lane l owns cols {2l, 2l+1}; wave walks the node's
// bucket (contiguous 128B row, scalar loads); m = gamma*xw[src]+beta via one
// __hfma2, f32 register accumulation. 4-edge unroll pipelines gather latency.
// ---------------------------------------------------------------------------
__global__ __launch_bounds__(256)
void agg_kernel(const unsigned int* __restrict__ bucket, const int* __restrict__ cnt,
                const float* __restrict__ x, const unsigned short* __restrict__ xwb,
                const unsigned short* __restrict__ gbt, const float* __restrict__ eps,
                unsigned short* __restrict__ o) {
  const int lane = threadIdx.x & 63;
  const int n = __builtin_amdgcn_readfirstlane(blockIdx.x * 4 + (threadIdx.x >> 6));
  int cn = cnt[n]; if (cn > CAP) cn = CAP;
  const unsigned int* bk = bucket + (size_t)n * CAP;

  float acc0 = 0.0f, acc1 = 0.0f;
  int e = 0;
  for (; e + 4 <= cn; e += 4) {
    unsigned int d0 = bk[e], d1 = bk[e + 1], d2 = bk[e + 2], d3 = bk[e + 3];
    __half2 x0 = *(const __half2*)&xwb[(size_t)(d0 & 0x1FFFF) * D_DIM + lane * 2];
    __half2 x1 = *(const __half2*)&xwb[(size_t)(d1 & 0x1FFFF) * D_DIM + lane * 2];
    __half2 x2 = *(const __half2*)&xwb[(size_t)(d2 & 0x1FFFF) * D_DIM + lane * 2];
    __half2 x3 = *(const __half2*)&xwb[(size_t)(d3 & 0x1FFFF) * D_DIM + lane * 2];
    uint2 g0 = *(const uint2*)&gbt[(d0 >> 17) * 256 + lane * 4];
    uint2 g1 = *(const uint2*)&gbt[(d1 >> 17) * 256 + lane * 4];
    uint2 g2 = *(const uint2*)&gbt[(d2 >> 17) * 256 + lane * 4];
    uint2 g3 = *(const uint2*)&gbt[(d3 >> 17) * 256 + lane * 4];
    __half2 m0 = __hfma2(u2h(g0.x), x0, u2h(g0.y));
    __half2 m1 = __hfma2(u2h(g1.x), x1, u2h(g1.y));
    __half2 m2 = __hfma2(u2h(g2.x), x2, u2h(g2.y));
    __half2 m3 = __hfma2(u2h(g3.x), x3, u2h(g3.y));
    float2 f0 = __half22float2(m0), f1 = __half22float2(m1);
    float2 f2 = __half22float2(m2), f3 = __half22float2(m3);
    acc0 += (f0.x + f1.x) + (f2.x + f3.x);
    acc1 += (f0.y + f1.y) + (f2.y + f3.y);
  }
  if (e + 2 <= cn) {
    unsigned int d0 = bk[e], d1 = bk[e + 1];
    __half2 x0 = *(const __half2*)&xwb[(size_t)(d0 & 0x1FFFF) * D_DIM + lane * 2];
    __half2 x1 = *(const __half2*)&xwb[(size_t)(d1 & 0x1FFFF) * D_DIM + lane * 2];
    uint2 g0 = *(const uint2*)&gbt[(d0 >> 17) * 256 + lane * 4];
    uint2 g1 = *(const uint2*)&gbt[(d1 >> 17) * 256 + lane * 4];
    __half2 m0 = __hfma2(u2h(g0.x), x0, u2h(g0.y));
    __half2 m1 = __hfma2(u2h(g1.x), x1, u2h(g1.y));
    float2 f0 = __half22float2(m0), f1 = __half22float2(m1);
    acc0 += f0.x + f1.x;
    acc1 += f0.y + f1.y;
    e += 2;
  }
  if (e < cn) {
    unsigned int d0 = bk[e];
    __half2 x0 = *(const __half2*)&xwb[(size_t)(d0 & 0x1FFFF) * D_DIM + lane * 2];
    uint2 g0 = *(const uint2*)&gbt[(d0 >> 17) * 256 + lane * 4];
    __half2 m0 = __hfma2(u2h(g0.x), x0, u2h(g0.y));
    float2 f0 = __half22float2(m0);
    acc0 += f0.x;
    acc1 += f0.y;
  }

  const float e1v = 1.0f + eps[0];
  float2 xr = *(const float2*)&x[(size_t)n * D_DIM + lane * 2];
  unsigned int w = (unsigned int)f32_to_bf16(e1v * xr.x + acc0)
                 | ((unsigned int)f32_to_bf16(e1v * xr.y + acc1) << 16);
  *(unsigned int*)&o[(size_t)n * D_DIM + lane * 2] = w;
}

// ---------------------------------------------------------------------------
// mlp: block = 128 nodes, 8 waves. All outputs staged through LDS and written
// as full cache lines (float4 / short8 rows) — no partial-line amplification.
// LDS overlay timeline in one 67584 B buffer:
//   o tile [128][136]bf16 -> t tile [128][264]bf16 -> y tile [128][132]f32
//   -> (D) xw tile [128][136]f16
// ---------------------------------------------------------------------------
__global__ __launch_bounds__(512, 4)
void mlp_kernel(const unsigned short* __restrict__ o,
                const unsigned short* __restrict__ w0b, const float* __restrict__ b0,
                const unsigned short* __restrict__ w1b, const float* __restrict__ b1,
                float* __restrict__ y,
                const unsigned short* __restrict__ WwNb,  // next-layer Ww bf16 (or null)
                const float* __restrict__ WbN,            // next-layer bias
                unsigned short* __restrict__ xwbN) {      // next-layer xw f16 out
  __shared__ unsigned short u_lds[MROWS * LDT];   // 67584 B
  unsigned short* a_lds = u_lds;          // [128][LDA] bf16 o tile
  unsigned short* t_lds = u_lds;          // [128][LDT] bf16 t tile
  float*          yf    = (float*)u_lds;  // [128][LDFY] f32 y tile
  unsigned short* xs    = u_lds;          // [128][LDA] f16 xw tile

  const int tid = threadIdx.x;     // 0..511
  const int m0 = blockIdx.x * MROWS;

  // ---- stage o tile (clamp tail rows)
  for (int i = tid; i < MROWS * 16; i += 512) {
    int row = i >> 4, seg = i & 15;
    int rg = m0 + row; if (rg >= N_NODES) rg = N_NODES - 1;
    *(short8*)&a_lds[row * LDA + seg * 8] =
        *(const short8*)&o[(size_t)rg * D_DIM + seg * 8];
  }
  __syncthreads();

  const int wave = tid >> 6, lane = tid & 63;
  const int lrow = lane & 15, quad = lane >> 4;

  // ---- B: t = relu(o @ w0^T + b0); wave covers t cols [wave*32, +32)
  {
    const int n0 = wave * 32;
    f32x4 acc[8][2] = {};
    #pragma unroll
    for (int ks = 0; ks < 128; ks += 32) {
      short8 bf0 = *(const short8*)&w0b[(n0 + lrow) * D_DIM + ks + quad * 8];
      short8 bf1 = *(const short8*)&w0b[(n0 + 16 + lrow) * D_DIM + ks + quad * 8];
      #pragma unroll
      for (int mt = 0; mt < 8; ++mt) {
        short8 a = *(const short8*)&a_lds[(mt * 16 + lrow) * LDA + ks + quad * 8];
        acc[mt][0] = __builtin_amdgcn_mfma_f32_16x16x32_bf16(a, bf0, acc[mt][0], 0, 0, 0);
        acc[mt][1] = __builtin_amdgcn_mfma_f32_16x16x32_bf16(a, bf1, acc[mt][1], 0, 0, 0);
      }
    }
    __syncthreads();   // a dead
    float bb0 = b0[n0 + lrow], bb1 = b0[n0 + 16 + lrow];
    #pragma unroll
    for (int mt = 0; mt < 8; ++mt)
      #pragma unroll
      for (int rr = 0; rr < 4; ++rr) {
        int row = mt * 16 + quad * 4 + rr;
        t_lds[row * LDT + n0 + lrow]      = f32_to_bf16(fmaxf(acc[mt][0][rr] + bb0, 0.0f));
        t_lds[row * LDT + n0 + 16 + lrow] = f32_to_bf16(fmaxf(acc[mt][1][rr] + bb1, 0.0f));
      }
  }
  __syncthreads();

  // ---- C: y = t @ w1^T + b1; wave covers y cols [wave*16, +16)
  {
    const int n0 = wave * 16;
    f32x4 acc[8] = {};
    #pragma unroll
    for (int ks = 0; ks < 256; ks += 32) {
      short8 bf = *(const short8*)&w1b[(n0 + lrow) * 2 * D_DIM + ks + quad * 8];
      #pragma unroll
      for (int mt = 0; mt < 8; ++mt) {
        short8 a = *(const short8*)&t_lds[(mt * 16 + lrow) * LDT + ks + quad * 8];
        acc[mt] = __builtin_amdgcn_mfma_f32_16x16x32_bf16(a, bf, acc[mt], 0, 0, 0);
      }
    }
    __syncthreads();   // t dead
    float bb = b1[n0 + lrow];
    #pragma unroll
    for (int mt = 0; mt < 8; ++mt)
      #pragma unroll
      for (int rr = 0; rr < 4; ++rr) {
        int row = mt * 16 + quad * 4 + rr;
        yf[row * LDFY + n0 + lrow] = acc[mt][rr] + bb;
      }
  }
  __syncthreads();   // y tile complete

  // ---- cooperative y write: full 512B rows, float4 per lane
  for (int i = tid; i < MROWS * 32; i += 512) {
    int row = i >> 5, c4 = i & 31;
    int rg = m0 + row;
    if (rg < N_NODES)
      *(float4*)&y[(size_t)rg * D_DIM + c4 * 4] = *(const float4*)&yf[row * LDFY + c4 * 4];
  }

  // ---- D (fused next-layer xw): xwbN = f16(y @ WwN^T + WbN)
  if (xwbN) {
    const int n0 = wave * 16;
    f32x4 acc[8] = {};
    #pragma unroll
    for (int ks = 0; ks < 128; ks += 32) {
      short8 bf = *(const short8*)&WwNb[(n0 + lrow) * D_DIM + ks + quad * 8];
      #pragma unroll
      for (int mt = 0; mt < 8; ++mt) {
        short8 a = frag_from_f32(&yf[(mt * 16 + lrow) * LDFY + ks + quad * 8]);
        acc[mt] = __builtin_amdgcn_mfma_f32_16x16x32_bf16(a, bf, acc[mt], 0, 0, 0);
      }
    }
    __syncthreads();   // yf dead (also guarantees y-write loop reads done)
    float bb = WbN[n0 + lrow];
    #pragma unroll
    for (int mt = 0; mt < 8; ++mt)
      #pragma unroll
      for (int rr = 0; rr < 4; ++rr) {
        int row = mt * 16 + quad * 4 + rr;
        xs[row * LDA + n0 + lrow] = f2h(acc[mt][rr] + bb);
      }
    __syncthreads();   // xw tile complete
    // cooperative xwb write: full 256B rows, short8 per lane
    for (int i = tid; i < MROWS * 16; i += 512) {
      int row = i >> 4, seg = i & 15;
      int rg = m0 + row;
      if (rg < N_NODES)
        *(short8*)&xwbN[(size_t)rg * D_DIM + seg * 8] = *(const short8*)&xs[row * LDA + seg * 8];
    }
  }
}

// ---------------------------------------------------------------------------
extern "C" void kernel_launch(void* const* d_in, const int* in_sizes, int n_in,
                              void* d_out, int out_size, void* d_ws, size_t ws_size,
                              hipStream_t stream) {
  const int*   ei      = (const int*)d_in[0];
  const int*   et      = (const int*)d_in[1];
  const float* embed   = (const float*)d_in[2];
  const float* rel_emb = (const float*)d_in[3];
  const float* rmw0 = (const float*)d_in[4];  const float* rmb0 = (const float*)d_in[5];
  const float* rmw1 = (const float*)d_in[6];  const float* rmb1 = (const float*)d_in[7];
  const float* rmw2 = (const float*)d_in[8];  const float* rmb2 = (const float*)d_in[9];
  const float* rmw3 = (const float*)d_in[10]; const float* rmb3 = (const float*)d_in[11];
  const float* Ww   = (const float*)d_in[12]; const float* Wb   = (const float*)d_in[13];
  const float* mw0  = (const float*)d_in[14]; const float* mb0  = (const float*)d_in[15];
  const float* mw1  = (const float*)d_in[16]; const float* mb1  = (const float*)d_in[17];
  const float* eps  = (const float*)d_in[18];
  float* out = (float*)d_out;

  // workspace layout
  float*          W1   = (float*)d_ws;                          // N*D f32
  unsigned short* xwb  = (unsigned short*)(W1 + (size_t)N_NODES * D_DIM);  // N*D f16
  unsigned short* gbb  = xwb + (size_t)N_NODES * D_DIM;         // L*R*256 f16
  unsigned short* Wwb  = gbb + L_LAYERS * R_REL * 256;          // L*128*128 bf16
  unsigned short* mw0b = Wwb + L_LAYERS * D_DIM * D_DIM;        // L*256*128 bf16
  unsigned short* mw1b = mw0b + L_LAYERS * 2 * D_DIM * D_DIM;   // L*128*256 bf16
  int*   cnt     = (int*)(mw1b + L_LAYERS * 2 * D_DIM * D_DIM); // N
  unsigned int* bucket = (unsigned int*)(cnt + N_NODES);        // N*CAP u32
  unsigned short* obuf = (unsigned short*)(bucket + (size_t)N_NODES * CAP); // N*D bf16

  // ---- preprocessing: scatter ∪ prep ∪ conv, then slim xw(L0)
  hipMemsetAsync(cnt, 0, N_NODES * sizeof(int), stream);
  scatter_prep_conv_kernel<<<SPC_BLKS, 512, 0, stream>>>(
      ei, et, cnt, bucket, rel_emb,
      rmw0, rmb0, rmw1, rmb1, rmw2, rmb2, rmw3, rmb3, gbb,
      Ww, mw0, mw1, Wwb, mw0b, mw1b);
  xw_kernel<<<GMLP, 512, 0, stream>>>(embed, Ww, Wb, xwb);

  const int gA = N_NODES / 4;         // 25000 (wave per node)

  // ---- layer 0 (mlp fuses next-layer xw as phase D)
  agg_kernel<<<gA, 256, 0, stream>>>(bucket, cnt, embed, xwb, gbb, eps, obuf);
  mlp_kernel<<<GMLP, 512, 0, stream>>>(obuf, mw0b, mb0, mw1b, mb1, W1,
                                       Wwb + D_DIM * D_DIM, Wb + D_DIM, xwb);

  // ---- layer 1
  agg_kernel<<<gA, 256, 0, stream>>>(bucket, cnt, W1, xwb,
                                     gbb + R_REL * 256, eps + 1, obuf);
  mlp_kernel<<<GMLP, 512, 0, stream>>>(obuf, mw0b + 2 * D_DIM * D_DIM, mb0 + 2 * D_DIM,
                                       mw1b + 2 * D_DIM * D_DIM, mb1 + D_DIM, out,
                                       nullptr, nullptr, nullptr);
}

// Round 13
// 374.127 us; speedup vs baseline: 1.0301x; 1.0301x over previous
//
#include <hip/hip_runtime.h>
#include <hip/hip_fp16.h>
#include <stdint.h>

#define N_NODES 100000
#define N_EDGES 640000
#define R_REL   64
#define D_DIM   128
#define L_LAYERS 2

#define CAP 32            // bucket capacity per node (P(deg>=32)~4e-13; verified no drops R8-R12)

#define LDA 136   // bf16 tile stride (128 + 8 pad)
#define LDT 264   // bf16 t-tile stride (256 + 8 pad)
#define LDFY 132  // f32 y-tile stride (128 + 4 pad)
#define LDP 264   // f16 prep activation stride (256 + 8 pad)
#define MROWS 128 // mlp/xw tile rows
#define GMLP ((N_NODES + MROWS - 1) / MROWS)   // 782

#define SCAT_BLKS  (N_EDGES / 512)   // 1250 (512 thr/block)
#define PREP_BLKS  2                 // prep role (one per layer l)
#define CONV_BLKS  128               // weight convert role (512 thr each)
#define SPC_BLKS   (SCAT_BLKS + PREP_BLKS + CONV_BLKS)   // 1380

typedef __attribute__((ext_vector_type(8))) short    short8;   // 8 bf16 MFMA frag
typedef __attribute__((ext_vector_type(8))) _Float16 half8;    // 8 f16 MFMA frag
typedef __attribute__((ext_vector_type(4))) unsigned short ushort4v;
typedef __attribute__((ext_vector_type(4))) float    f32x4;

__device__ __forceinline__ unsigned short f32_to_bf16(float f) {
  union { float f; uint32_t u; } v; v.f = f;
  uint32_t u = v.u;
  u += 0x7fffu + ((u >> 16) & 1u);   // RNE (finite inputs only)
  return (unsigned short)(u >> 16);
}
__device__ __forceinline__ unsigned short f2h(float f) {
  __half h = __float2half(f);
  return __half_as_ushort(h);
}
__device__ __forceinline__ __half2 u2h(unsigned int u) {
  union { unsigned int u; __half2 h; } v; v.u = u; return v.h;
}
__device__ __forceinline__ short8 frag_from_f32(const float* p) {
  float4 a = *(const float4*)p;
  float4 b = *(const float4*)(p + 4);
  short8 r;
  r[0] = (short)f32_to_bf16(a.x); r[1] = (short)f32_to_bf16(a.y);
  r[2] = (short)f32_to_bf16(a.z); r[3] = (short)f32_to_bf16(a.w);
  r[4] = (short)f32_to_bf16(b.x); r[5] = (short)f32_to_bf16(b.y);
  r[6] = (short)f32_to_bf16(b.z); r[7] = (short)f32_to_bf16(b.w);
  return r;
}
__device__ __forceinline__ half8 hfrag_from_f32(const float* p) {
  float4 a = *(const float4*)p;
  float4 b = *(const float4*)(p + 4);
  half8 r;
  r[0] = (_Float16)a.x; r[1] = (_Float16)a.y;
  r[2] = (_Float16)a.z; r[3] = (_Float16)a.w;
  r[4] = (_Float16)b.x; r[5] = (_Float16)b.y;
  r[6] = (_Float16)b.z; r[7] = (_Float16)b.w;
  return r;
}

// ---------------------------------------------------------------------------
// prep GEMM phase (8 waves x 32 cols), IN-PLACE on one [64][LDP] buffer:
// the whole output tile lives in acc registers before any write, so
// K-loop-read -> barrier -> write-back needs no second buffer (R12 fix: the
// 2-buffer version's 67.6KB static LDS capped the co-resident scatter role
// at 2 blocks/CU and stretched the atomic pass 55->93us).
// f16 MFMA, f32 acc; final phase writes packed gbb {g2l,g2l+1,b2l,b2l+1}.
// ---------------------------------------------------------------------------
template<int K, bool RELU, bool FINAL>
__device__ __forceinline__ void prep_gemm(unsigned short* __restrict__ buf,
                                          const float* __restrict__ W,
                                          const float* __restrict__ bias,
                                          unsigned short* __restrict__ gbb_l,
                                          int wave, int lrow, int quad) {
  const int n0 = wave * 32;
  f32x4 acc[4][2] = {};
  for (int ks = 0; ks < K; ks += 32) {
    half8 bf[2];
    #pragma unroll
    for (int nt = 0; nt < 2; ++nt)
      bf[nt] = hfrag_from_f32(&W[(size_t)(n0 + nt * 16 + lrow) * K + ks + quad * 8]);
    #pragma unroll
    for (int mt = 0; mt < 4; ++mt) {
      half8 a = *(const half8*)&buf[(mt * 16 + lrow) * LDP + ks + quad * 8];
      #pragma unroll
      for (int nt = 0; nt < 2; ++nt)
        acc[mt][nt] = __builtin_amdgcn_mfma_f32_16x16x32_f16(a, bf[nt], acc[mt][nt], 0, 0, 0);
    }
  }
  __syncthreads();   // all reads of buf complete before in-place overwrite
  #pragma unroll
  for (int mt = 0; mt < 4; ++mt)
    #pragma unroll
    for (int nt = 0; nt < 2; ++nt) {
      int col = n0 + nt * 16 + lrow;
      float bb = bias[col];
      #pragma unroll
      for (int rr = 0; rr < 4; ++rr) {
        int row = mt * 16 + quad * 4 + rr;
        float v = acc[mt][nt][rr] + bb;
        if (RELU) v = fmaxf(v, 0.f);
        if (!FINAL) {
          buf[row * LDP + col] = f2h(v);
        } else {
          int slot = (col < D_DIM) ? ((col >> 1) * 4 + (col & 1))
                                   : (((col - D_DIM) >> 1) * 4 + 2 + ((col - D_DIM) & 1));
          gbb_l[row * 256 + slot] = f2h(v);
        }
      }
    }
}

// ---------------------------------------------------------------------------
// scatter ∪ prep ∪ conv. LDS = 33.8KB (single prep buffer) -> 4 blocks/CU
// -> the scatter role keeps full 2048-thread/CU wave capacity.
//  [0, 1250)      bucket scatter (512 thr): slot=atomicAdd(cnt[dst]);
//                 bucket[dst*32+slot] = src | (type<<17)
//  [1250, 1252)   prep: 4-layer GEMM chain -> packed gbb (8 waves, MFMA)
//  [1252, 1380)   weight f32->bf16 conversion
// ---------------------------------------------------------------------------
__global__ __launch_bounds__(512)
void scatter_prep_conv_kernel(const int* __restrict__ ei, const int* __restrict__ et,
                              int* __restrict__ cnt, unsigned int* __restrict__ bucket,
                              const float* __restrict__ rel_emb,
                              const float* __restrict__ rmw0, const float* __restrict__ rmb0,
                              const float* __restrict__ rmw1, const float* __restrict__ rmb1,
                              const float* __restrict__ rmw2, const float* __restrict__ rmb2,
                              const float* __restrict__ rmw3, const float* __restrict__ rmb3,
                              unsigned short* __restrict__ gbb,
                              const float* __restrict__ Ww, const float* __restrict__ mw0,
                              const float* __restrict__ mw1,
                              unsigned short* __restrict__ Wwb, unsigned short* __restrict__ mw0b,
                              unsigned short* __restrict__ mw1b) {
  __shared__ unsigned short buf[64 * LDP];   // 33792 B (prep role only)
  const int b = blockIdx.x;
  const int tid = threadIdx.x;     // 0..511

  if (b < SCAT_BLKS) {                         // ---- scatter role
    int idx = b * 512 + tid;
    int dst = ei[N_EDGES + idx];
    int slot = atomicAdd(&cnt[dst], 1);
    if (slot < CAP)
      bucket[(size_t)dst * CAP + slot] =
          (unsigned int)ei[idx] | ((unsigned int)et[idx] << 17);
    return;
  }

  const int wave = tid >> 6, lane = tid & 63;
  const int lrow = lane & 15, quad = lane >> 4;

  if (b < SCAT_BLKS + PREP_BLKS) {             // ---- prep role (l = b - SCAT_BLKS)
    const int l = b - SCAT_BLKS;
    for (int i = tid; i < 64 * 32; i += 512) {
      int row = i >> 5, c4 = i & 31;
      float4 v = *(const float4*)&rel_emb[(size_t)(l * R_REL + row) * D_DIM + c4 * 4];
      ushort4v s;
      s[0] = f2h(v.x); s[1] = f2h(v.y); s[2] = f2h(v.z); s[3] = f2h(v.w);
      *(ushort4v*)&buf[row * LDP + c4 * 4] = s;
    }
    __syncthreads();
    prep_gemm<128, true, false>(buf, rmw0 + (size_t)l * 256 * 128, rmb0 + l * 256,
                                nullptr, wave, lrow, quad);
    __syncthreads();
    prep_gemm<256, true, false>(buf, rmw1 + (size_t)l * 256 * 256, rmb1 + l * 256,
                                nullptr, wave, lrow, quad);
    __syncthreads();
    prep_gemm<256, true, false>(buf, rmw2 + (size_t)l * 256 * 256, rmb2 + l * 256,
                                nullptr, wave, lrow, quad);
    __syncthreads();
    prep_gemm<256, false, true>(buf, rmw3 + (size_t)l * 256 * 256, rmb3 + l * 256,
                                gbb + (size_t)l * R_REL * 256, wave, lrow, quad);
    return;
  }

  // ---- weight convert role
  {
    int i = (b - SCAT_BLKS - PREP_BLKS) * 512 + tid;   // 0..65535
    if (i < L_LAYERS * D_DIM * D_DIM)     Wwb[i]  = f32_to_bf16(Ww[i]);
    if (i < L_LAYERS * 2 * D_DIM * D_DIM) mw0b[i] = f32_to_bf16(mw0[i]);
    if (i < L_LAYERS * 2 * D_DIM * D_DIM) mw1b[i] = f32_to_bf16(mw1[i]);
  }
}

// ---------------------------------------------------------------------------
// xw(L0): slim standalone kernel (34.8KB LDS -> 4 blocks/CU; 782 blocks fit
// in one occupancy round). 128-row tiles, 8 MFMA per weight load,
// LDS-staged full-row output writes.
// ---------------------------------------------------------------------------
__global__ __launch_bounds__(512, 8)
void xw_kernel(const float* __restrict__ x, const float* __restrict__ Ww,
               const float* __restrict__ Wb, unsigned short* __restrict__ xwb) {
  __shared__ unsigned short a_lds[MROWS * LDA];   // 34816 B
  const int tid = threadIdx.x;     // 0..511
  const int m0 = blockIdx.x * MROWS;
  const int wave = tid >> 6, lane = tid & 63;
  const int lrow = lane & 15, quad = lane >> 4;

  for (int i = tid; i < MROWS * 32; i += 512) {
    int row = i >> 5, c4 = i & 31;
    int rg = m0 + row; if (rg >= N_NODES) rg = N_NODES - 1;
    float4 v = *(const float4*)&x[(size_t)rg * D_DIM + c4 * 4];
    ushort4v s;
    s[0] = f32_to_bf16(v.x); s[1] = f32_to_bf16(v.y);
    s[2] = f32_to_bf16(v.z); s[3] = f32_to_bf16(v.w);
    *(ushort4v*)&a_lds[row * LDA + c4 * 4] = s;
  }
  __syncthreads();

  const int n0 = wave * 16;
  f32x4 acc[8] = {};
  #pragma unroll
  for (int ks = 0; ks < 128; ks += 32) {
    short8 bf = frag_from_f32(&Ww[(size_t)(n0 + lrow) * D_DIM + ks + quad * 8]);
    #pragma unroll
    for (int mt = 0; mt < 8; ++mt) {
      short8 a = *(const short8*)&a_lds[(mt * 16 + lrow) * LDA + ks + quad * 8];
      acc[mt] = __builtin_amdgcn_mfma_f32_16x16x32_bf16(a, bf, acc[mt], 0, 0, 0);
    }
  }
  __syncthreads();   // a tile dead -> overlay xw f16 tile
  float bb = Wb[n0 + lrow];
  #pragma unroll
  for (int mt = 0; mt < 8; ++mt)
    #pragma unroll
    for (int rr = 0; rr < 4; ++rr) {
      int row = mt * 16 + quad * 4 + rr;
      a_lds[row * LDA + n0 + lrow] = f2h(acc[mt][rr] + bb);
    }
  __syncthreads();
  // cooperative full-row writes (short8): no partial-line amplification
  for (int i = tid; i < MROWS * 16; i += 512) {
    int row = i >> 4, seg = i & 15;
    int rg = m0 + row;
    if (rg < N_NODES)
      *(short8*)&xwb[(size_t)rg * D_DIM + seg * 8] = *(const short8*)&a_lds[row * LDA + seg * 8];
  }
}

// ---------------------------------------------------------------------------
// agg: one WAVE per node. Lane l owns cols {2l, 2l+1}; wave walks the node's
// bucket (contiguous 128B row, scalar loads); m = gamma*xw[src]+beta via one
// __hfma2, f32 register accumulation. 4-edge unroll pipelines gather latency.
// ---------------------------------------------------------------------------
__global__ __launch_bounds__(256)
void agg_kernel(const unsigned int* __restrict__ bucket, const int* __restrict__ cnt,
                const float* __restrict__ x, const unsigned short* __restrict__ xwb,
                const unsigned short* __restrict__ gbt, const float* __restrict__ eps,
                unsigned short* __restrict__ o) {
  const int lane = threadIdx.x & 63;
  const int n = __builtin_amdgcn_readfirstlane(blockIdx.x * 4 + (threadIdx.x >> 6));
  int cn = cnt[n]; if (cn > CAP) cn = CAP;
  const unsigned int* bk = bucket + (size_t)n * CAP;

  float acc0 = 0.0f, acc1 = 0.0f;
  int e = 0;
  for (; e + 4 <= cn; e += 4) {
    unsigned int d0 = bk[e], d1 = bk[e + 1], d2 = bk[e + 2], d3 = bk[e + 3];
    __half2 x0 = *(const __half2*)&xwb[(size_t)(d0 & 0x1FFFF) * D_DIM + lane * 2];
    __half2 x1 = *(const __half2*)&xwb[(size_t)(d1 & 0x1FFFF) * D_DIM + lane * 2];
    __half2 x2 = *(const __half2*)&xwb[(size_t)(d2 & 0x1FFFF) * D_DIM + lane * 2];
    __half2 x3 = *(const __half2*)&xwb[(size_t)(d3 & 0x1FFFF) * D_DIM + lane * 2];
    uint2 g0 = *(const uint2*)&gbt[(d0 >> 17) * 256 + lane * 4];
    uint2 g1 = *(const uint2*)&gbt[(d1 >> 17) * 256 + lane * 4];
    uint2 g2 = *(const uint2*)&gbt[(d2 >> 17) * 256 + lane * 4];
    uint2 g3 = *(const uint2*)&gbt[(d3 >> 17) * 256 + lane * 4];
    __half2 m0 = __hfma2(u2h(g0.x), x0, u2h(g0.y));
    __half2 m1 = __hfma2(u2h(g1.x), x1, u2h(g1.y));
    __half2 m2 = __hfma2(u2h(g2.x), x2, u2h(g2.y));
    __half2 m3 = __hfma2(u2h(g3.x), x3, u2h(g3.y));
    float2 f0 = __half22float2(m0), f1 = __half22float2(m1);
    float2 f2 = __half22float2(m2), f3 = __half22float2(m3);
    acc0 += (f0.x + f1.x) + (f2.x + f3.x);
    acc1 += (f0.y + f1.y) + (f2.y + f3.y);
  }
  if (e + 2 <= cn) {
    unsigned int d0 = bk[e], d1 = bk[e + 1];
    __half2 x0 = *(const __half2*)&xwb[(size_t)(d0 & 0x1FFFF) * D_DIM + lane * 2];
    __half2 x1 = *(const __half2*)&xwb[(size_t)(d1 & 0x1FFFF) * D_DIM + lane * 2];
    uint2 g0 = *(const uint2*)&gbt[(d0 >> 17) * 256 + lane * 4];
    uint2 g1 = *(const uint2*)&gbt[(d1 >> 17) * 256 + lane * 4];
    __half2 m0 = __hfma2(u2h(g0.x), x0, u2h(g0.y));
    __half2 m1 = __hfma2(u2h(g1.x), x1, u2h(g1.y));
    float2 f0 = __half22float2(m0), f1 = __half22float2(m1);
    acc0 += f0.x + f1.x;
    acc1 += f0.y + f1.y;
    e += 2;
  }
  if (e < cn) {
    unsigned int d0 = bk[e];
    __half2 x0 = *(const __half2*)&xwb[(size_t)(d0 & 0x1FFFF) * D_DIM + lane * 2];
    uint2 g0 = *(const uint2*)&gbt[(d0 >> 17) * 256 + lane * 4];
    __half2 m0 = __hfma2(u2h(g0.x), x0, u2h(g0.y));
    float2 f0 = __half22float2(m0);
    acc0 += f0.x;
    acc1 += f0.y;
  }

  const float e1v = 1.0f + eps[0];
  float2 xr = *(const float2*)&x[(size_t)n * D_DIM + lane * 2];
  unsigned int w = (unsigned int)f32_to_bf16(e1v * xr.x + acc0)
                 | ((unsigned int)f32_to_bf16(e1v * xr.y + acc1) << 16);
  *(unsigned int*)&o[(size_t)n * D_DIM + lane * 2] = w;
}

// ---------------------------------------------------------------------------
// mlp: block = 128 nodes, 8 waves. All outputs staged through LDS and written
// as full cache lines (float4 / short8 rows) — no partial-line amplification.
// LDS overlay timeline in one 67584 B buffer:
//   o tile [128][136]bf16 -> t tile [128][264]bf16 -> y tile [128][132]f32
//   -> (D) xw tile [128][136]f16
// ---------------------------------------------------------------------------
__global__ __launch_bounds__(512, 4)
void mlp_kernel(const unsigned short* __restrict__ o,
                const unsigned short* __restrict__ w0b, const float* __restrict__ b0,
                const unsigned short* __restrict__ w1b, const float* __restrict__ b1,
                float* __restrict__ y,
                const unsigned short* __restrict__ WwNb,  // next-layer Ww bf16 (or null)
                const float* __restrict__ WbN,            // next-layer bias
                unsigned short* __restrict__ xwbN) {      // next-layer xw f16 out
  __shared__ unsigned short u_lds[MROWS * LDT];   // 67584 B
  unsigned short* a_lds = u_lds;          // [128][LDA] bf16 o tile
  unsigned short* t_lds = u_lds;          // [128][LDT] bf16 t tile
  float*          yf    = (float*)u_lds;  // [128][LDFY] f32 y tile
  unsigned short* xs    = u_lds;          // [128][LDA] f16 xw tile

  const int tid = threadIdx.x;     // 0..511
  const int m0 = blockIdx.x * MROWS;

  // ---- stage o tile (clamp tail rows)
  for (int i = tid; i < MROWS * 16; i += 512) {
    int row = i >> 4, seg = i & 15;
    int rg = m0 + row; if (rg >= N_NODES) rg = N_NODES - 1;
    *(short8*)&a_lds[row * LDA + seg * 8] =
        *(const short8*)&o[(size_t)rg * D_DIM + seg * 8];
  }
  __syncthreads();

  const int wave = tid >> 6, lane = tid & 63;
  const int lrow = lane & 15, quad = lane >> 4;

  // ---- B: t = relu(o @ w0^T + b0); wave covers t cols [wave*32, +32)
  {
    const int n0 = wave * 32;
    f32x4 acc[8][2] = {};
    #pragma unroll
    for (int ks = 0; ks < 128; ks += 32) {
      short8 bf0 = *(const short8*)&w0b[(n0 + lrow) * D_DIM + ks + quad * 8];
      short8 bf1 = *(const short8*)&w0b[(n0 + 16 + lrow) * D_DIM + ks + quad * 8];
      #pragma unroll
      for (int mt = 0; mt < 8; ++mt) {
        short8 a = *(const short8*)&a_lds[(mt * 16 + lrow) * LDA + ks + quad * 8];
        acc[mt][0] = __builtin_amdgcn_mfma_f32_16x16x32_bf16(a, bf0, acc[mt][0], 0, 0, 0);
        acc[mt][1] = __builtin_amdgcn_mfma_f32_16x16x32_bf16(a, bf1, acc[mt][1], 0, 0, 0);
      }
    }
    __syncthreads();   // a dead
    float bb0 = b0[n0 + lrow], bb1 = b0[n0 + 16 + lrow];
    #pragma unroll
    for (int mt = 0; mt < 8; ++mt)
      #pragma unroll
      for (int rr = 0; rr < 4; ++rr) {
        int row = mt * 16 + quad * 4 + rr;
        t_lds[row * LDT + n0 + lrow]      = f32_to_bf16(fmaxf(acc[mt][0][rr] + bb0, 0.0f));
        t_lds[row * LDT + n0 + 16 + lrow] = f32_to_bf16(fmaxf(acc[mt][1][rr] + bb1, 0.0f));
      }
  }
  __syncthreads();

  // ---- C: y = t @ w1^T + b1; wave covers y cols [wave*16, +16)
  {
    const int n0 = wave * 16;
    f32x4 acc[8] = {};
    #pragma unroll
    for (int ks = 0; ks < 256; ks += 32) {
      short8 bf = *(const short8*)&w1b[(n0 + lrow) * 2 * D_DIM + ks + quad * 8];
      #pragma unroll
      for (int mt = 0; mt < 8; ++mt) {
        short8 a = *(const short8*)&t_lds[(mt * 16 + lrow) * LDT + ks + quad * 8];
        acc[mt] = __builtin_amdgcn_mfma_f32_16x16x32_bf16(a, bf, acc[mt], 0, 0, 0);
      }
    }
    __syncthreads();   // t dead
    float bb = b1[n0 + lrow];
    #pragma unroll
    for (int mt = 0; mt < 8; ++mt)
      #pragma unroll
      for (int rr = 0; rr < 4; ++rr) {
        int row = mt * 16 + quad * 4 + rr;
        yf[row * LDFY + n0 + lrow] = acc[mt][rr] + bb;
      }
  }
  __syncthreads();   // y tile complete

  // ---- cooperative y write: full 512B rows, float4 per lane
  for (int i = tid; i < MROWS * 32; i += 512) {
    int row = i >> 5, c4 = i & 31;
    int rg = m0 + row;
    if (rg < N_NODES)
      *(float4*)&y[(size_t)rg * D_DIM + c4 * 4] = *(const float4*)&yf[row * LDFY + c4 * 4];
  }

  // ---- D (fused next-layer xw): xwbN = f16(y @ WwN^T + WbN)
  if (xwbN) {
    const int n0 = wave * 16;
    f32x4 acc[8] = {};
    #pragma unroll
    for (int ks = 0; ks < 128; ks += 32) {
      short8 bf = *(const short8*)&WwNb[(n0 + lrow) * D_DIM + ks + quad * 8];
      #pragma unroll
      for (int mt = 0; mt < 8; ++mt) {
        short8 a = frag_from_f32(&yf[(mt * 16 + lrow) * LDFY + ks + quad * 8]);
        acc[mt] = __builtin_amdgcn_mfma_f32_16x16x32_bf16(a, bf, acc[mt], 0, 0, 0);
      }
    }
    __syncthreads();   // yf dead (also guarantees y-write loop reads done)
    float bb = WbN[n0 + lrow];
    #pragma unroll
    for (int mt = 0; mt < 8; ++mt)
      #pragma unroll
      for (int rr = 0; rr < 4; ++rr) {
        int row = mt * 16 + quad * 4 + rr;
        xs[row * LDA + n0 + lrow] = f2h(acc[mt][rr] + bb);
      }
    __syncthreads();   // xw tile complete
    // cooperative xwb write: full 256B rows, short8 per lane
    for (int i = tid; i < MROWS * 16; i += 512) {
      int row = i >> 4, seg = i & 15;
      int rg = m0 + row;
      if (rg < N_NODES)
        *(short8*)&xwbN[(size_t)rg * D_DIM + seg * 8] = *(const short8*)&xs[row * LDA + seg * 8];
    }
  }
}

// ---------------------------------------------------------------------------
extern "C" void kernel_launch(void* const* d_in, const int* in_sizes, int n_in,
                              void* d_out, int out_size, void* d_ws, size_t ws_size,
                              hipStream_t stream) {
  const int*   ei      = (const int*)d_in[0];
  const int*   et      = (const int*)d_in[1];
  const float* embed   = (const float*)d_in[2];
  const float* rel_emb = (const float*)d_in[3];
  const float* rmw0 = (const float*)d_in[4];  const float* rmb0 = (const float*)d_in[5];
  const float* rmw1 = (const float*)d_in[6];  const float* rmb1 = (const float*)d_in[7];
  const float* rmw2 = (const float*)d_in[8];  const float* rmb2 = (const float*)d_in[9];
  const float* rmw3 = (const float*)d_in[10]; const float* rmb3 = (const float*)d_in[11];
  const float* Ww   = (const float*)d_in[12]; const float* Wb   = (const float*)d_in[13];
  const float* mw0  = (const float*)d_in[14]; const float* mb0  = (const float*)d_in[15];
  const float* mw1  = (const float*)d_in[16]; const float* mb1  = (const float*)d_in[17];
  const float* eps  = (const float*)d_in[18];
  float* out = (float*)d_out;

  // workspace layout
  float*          W1   = (float*)d_ws;                          // N*D f32
  unsigned short* xwb  = (unsigned short*)(W1 + (size_t)N_NODES * D_DIM);  // N*D f16
  unsigned short* gbb  = xwb + (size_t)N_NODES * D_DIM;         // L*R*256 f16
  unsigned short* Wwb  = gbb + L_LAYERS * R_REL * 256;          // L*128*128 bf16
  unsigned short* mw0b = Wwb + L_LAYERS * D_DIM * D_DIM;        // L*256*128 bf16
  unsigned short* mw1b = mw0b + L_LAYERS * 2 * D_DIM * D_DIM;   // L*128*256 bf16
  int*   cnt     = (int*)(mw1b + L_LAYERS * 2 * D_DIM * D_DIM); // N
  unsigned int* bucket = (unsigned int*)(cnt + N_NODES);        // N*CAP u32
  unsigned short* obuf = (unsigned short*)(bucket + (size_t)N_NODES * CAP); // N*D bf16

  // ---- preprocessing: scatter ∪ prep ∪ conv (33.8KB LDS), then slim xw(L0)
  hipMemsetAsync(cnt, 0, N_NODES * sizeof(int), stream);
  scatter_prep_conv_kernel<<<SPC_BLKS, 512, 0, stream>>>(
      ei, et, cnt, bucket, rel_emb,
      rmw0, rmb0, rmw1, rmb1, rmw2, rmb2, rmw3, rmb3, gbb,
      Ww, mw0, mw1, Wwb, mw0b, mw1b);
  xw_kernel<<<GMLP, 512, 0, stream>>>(embed, Ww, Wb, xwb);

  const int gA = N_NODES / 4;         // 25000 (wave per node)

  // ---- layer 0 (mlp fuses next-layer xw as phase D)
  agg_kernel<<<gA, 256, 0, stream>>>(bucket, cnt, embed, xwb, gbb, eps, obuf);
  mlp_kernel<<<GMLP, 512, 0, stream>>>(obuf, mw0b, mb0, mw1b, mb1, W1,
                                       Wwb + D_DIM * D_DIM, Wb + D_DIM, xwb);

  // ---- layer 1
  agg_kernel<<<gA, 256, 0, stream>>>(bucket, cnt, W1, xwb,
                                     gbb + R_REL * 256, eps + 1, obuf);
  mlp_kernel<<<GMLP, 512, 0, stream>>>(obuf, mw0b + 2 * D_DIM * D_DIM, mb0 + 2 * D_DIM,
                                       mw1b + 2 * D_DIM * D_DIM, mb1 + D_DIM, out,
                                       nullptr, nullptr, nullptr);
}